// Round 2
// baseline (889.316 us; speedup 1.0000x reference)
//
#include <hip/hip_runtime.h>
#include <cstdint>
#include <cstddef>

typedef unsigned int u32;
typedef unsigned long long u64;

#define NTOT 122740      // total proposals per batch (4*(152^2+76^2+38^2+19^2))
#define KTOP 4096        // top-K candidates kept per batch for NMS
#define SCORE_T 0.25f

// level layout: [offset, count) per pyramid level
// L2: [0,      92416)  152x152 stride 4
// L3: [92416,  115520) 76x76   stride 8
// L4: [115520, 121296) 38x38   stride 16
// L5: [121296, 122740) 19x19   stride 32

// ---------------------------------------------------------------- kernel 0
__global__ void zero_counters_kernel(u32* c) {
  int t = threadIdx.x;
  if (t < 32) c[t] = 0u;
}

// ---------------------------------------------------------------- helpers
__device__ __forceinline__ float sigm(float x) { return 1.0f / (1.0f + expf(-x)); }

__device__ float4 decode_box_from_gidx(u32 gidx, int b,
    const float* __restrict__ p2, const float* __restrict__ p3,
    const float* __restrict__ p4, const float* __restrict__ p5)
{
  const float* p; int t, H, W; float stride;
  float aw0, ah0, aw1, ah1, aw2, ah2, aw3, ah3;
  if (gidx < 92416u) {
    p = p2; t = (int)gidx; H = 152; W = 152; stride = 4.0f;
    aw0=12.f; ah0=16.f; aw1=19.f; ah1=36.f; aw2=40.f; ah2=28.f; aw3=36.f; ah3=75.f;
  } else if (gidx < 115520u) {
    p = p3; t = (int)(gidx - 92416u); H = 76; W = 76; stride = 8.0f;
    aw0=36.f; ah0=75.f; aw1=76.f; ah1=55.f; aw2=72.f; ah2=146.f; aw3=142.f; ah3=110.f;
  } else if (gidx < 121296u) {
    p = p4; t = (int)(gidx - 115520u); H = 38; W = 38; stride = 16.0f;
    aw0=72.f; ah0=146.f; aw1=142.f; ah1=110.f; aw2=192.f; ah2=243.f; aw3=459.f; ah3=401.f;
  } else {
    p = p5; t = (int)(gidx - 121296u); H = 19; W = 19; stride = 32.0f;
    aw0=142.f; ah0=110.f; aw1=192.f; ah1=243.f; aw2=300.f; ah2=300.f; aw3=459.f; ah3=401.f;
  }
  int HW = H * W;
  int a = t / HW;
  int r = t - a * HW;
  int y = r / W;
  int x = r - y * W;
  const float* q = p + ((size_t)b * 4 * HW + (size_t)t) * 6;
  float2 t01 = *(const float2*)(q + 0);
  float2 t23 = *(const float2*)(q + 2);
  float cx = (sigm(t01.x) + (float)x) * stride;
  float cy = (sigm(t01.y) + (float)y) * stride;
  float aw = (a == 0) ? aw0 : (a == 1) ? aw1 : (a == 2) ? aw2 : aw3;
  float ah = (a == 0) ? ah0 : (a == 1) ? ah1 : (a == 2) ? ah2 : ah3;
  float bw = expf(t23.x) * aw;
  float bh = expf(t23.y) * ah;
  return make_float4(cx - 0.5f * bw, cy - 0.5f * bh, cx + 0.5f * bw, cy + 0.5f * bh);
}

// ---------------------------------------------------------------- kernel 1
template<int H, int W, int OFF>
__global__ void decode_kernel(const float* __restrict__ p, u32* __restrict__ counters,
                              uint2* __restrict__ pairs, int C,
                              float aw0, float ah0, float aw1, float ah1,
                              float aw2, float ah2, float aw3, float ah3)
{
  constexpr int HW = H * W;
  constexpr int AHW = 4 * HW;
  const int t = blockIdx.x * blockDim.x + threadIdx.x;
  const int b = blockIdx.y;
  bool inr = (t < AHW);
  float score = -1.0f;
  u32 gidx = 0;
  if (inr) {
    const float* q = p + ((size_t)b * AHW + (size_t)t) * 6;
    float2 t45 = *(const float2*)(q + 4);
    score = sigm(t45.x) * sigm(t45.y);
    gidx = (u32)(OFF + t);
  }
  // wave-aggregated compaction append (one atomic per wave)
  bool pred = inr && (score >= SCORE_T);
  u64 mask = __ballot(pred);
  if (mask != 0ull) {
    int lane = threadIdx.x & 63;
    int leader = (int)__ffsll((unsigned long long)mask) - 1;
    u32 base = 0;
    if (lane == leader) base = atomicAdd(&counters[b], (u32)__popcll(mask));
    base = (u32)__shfl((int)base, leader, 64);
    if (pred) {
      u32 pos = base + (u32)__popcll(mask & ((1ull << lane) - 1ull));
      if (pos < (u32)C) {
        pairs[(size_t)b * (size_t)C + pos] = make_uint2(__float_as_uint(score), gidx);
      }
    }
  }
}

// ---------------------------------------------------------------- kernel 2
__device__ __forceinline__ bool iou_gt(float4 A, float4 B) {
  // mirrors reference: inter/(a1+a2-inter+1e-9) > 0.5
  float ltx = fmaxf(A.x, B.x), lty = fmaxf(A.y, B.y);
  float rbx = fminf(A.z, B.z), rby = fminf(A.w, B.w);
  float w = fmaxf(rbx - ltx, 0.0f), h = fmaxf(rby - lty, 0.0f);
  float inter = w * h;
  float a1 = fmaxf(A.z - A.x, 0.0f) * fmaxf(A.w - A.y, 0.0f);
  float a2 = fmaxf(B.z - B.x, 0.0f) * fmaxf(B.w - B.y, 0.0f);
  float iou = inter / (a1 + a2 - inter + 1e-9f);
  return iou > 0.5f;
}

__global__ __launch_bounds__(1024, 1)
void nms_kernel(const uint2* __restrict__ pairs, const u32* __restrict__ counters, int C,
                const float* __restrict__ p2, const float* __restrict__ p3,
                const float* __restrict__ p4, const float* __restrict__ p5,
                float* __restrict__ out)
{
  const int b = blockIdx.x;
  const int tid = threadIdx.x;
  const uint2* bp = pairs + (size_t)b * (size_t)C;

  __shared__ u64 skey[KTOP];        // 32 KB  sort keys (inverted composite, ascending)
  __shared__ u32 hist[4096];        // 16 KB  histogram over score-bit bins
  __shared__ u32 scanbuf[1024];     // 4 KB   group suffix sums
  __shared__ float4 pbox[512];      // 8 KB   preloaded boxes for first 512 sorted
  __shared__ float4 selbox[100];    // 1.6 KB selected boxes
  __shared__ int s_misc[4];         // [0]=cutoff bin B, [1]=lds_n, [2]=n_sel

  int cnt = min((int)counters[b], C);

  // --- 1. histogram of score bits (scores in [0.25,1) -> bins 0..4095)
  for (int i = tid; i < 4096; i += 1024) hist[i] = 0u;
  if (tid == 0) { s_misc[1] = 0; }
  __syncthreads();
  for (int j = tid; j < cnt; j += 1024) {
    u32 bits = bp[j].x;
    int key = (int)((bits - 0x3E800000u) >> 12);
    key = max(0, min(4095, key));
    atomicAdd(&hist[key], 1u);
  }
  __syncthreads();

  // --- 2. group sums (4 bins/thread) + Hillis-Steele inclusive suffix scan
  u32 g = hist[4 * tid] + hist[4 * tid + 1] + hist[4 * tid + 2] + hist[4 * tid + 3];
  scanbuf[tid] = g;
  __syncthreads();
  for (int off = 1; off < 1024; off <<= 1) {
    u32 v = (tid + off < 1024) ? scanbuf[tid + off] : 0u;
    __syncthreads();
    scanbuf[tid] += v;
    __syncthreads();
  }
  // scanbuf[t] = cnt_ge(4t) = count of keys >= 4t (non-increasing in t)

  // --- 3. cutoff B = min{ b : cnt_ge(b) <= KTOP }  -> keep-set fits, DETERMINISTIC
  if (tid == 0 && scanbuf[0] <= (u32)KTOP) s_misc[0] = 0;   // everything fits: keep all
  {
    u32 nxt = (tid < 1023) ? scanbuf[tid + 1] : 0u;
    if (scanbuf[tid] > (u32)KTOP && nxt <= (u32)KTOP) {     // unique crossing group
      u32 c = nxt;                                          // = cnt_ge(4t+4) <= KTOP
      int B = 4 * tid + 4;
      for (int bin = 4 * tid + 3; bin >= 4 * tid; --bin) {
        c += hist[bin];                                     // = cnt_ge(bin)
        if (c <= (u32)KTOP) B = bin; else break;
      }
      s_misc[0] = B;
    }
  }
  __syncthreads();
  const int B = s_misc[0];

  // --- 4. compact keys >= B into LDS (guaranteed <= KTOP entries, no arbitrary drops)
  for (int j = tid; j < cnt; j += 1024) {
    u32 bits = bp[j].x;
    int key = (int)((bits - 0x3E800000u) >> 12);
    key = max(0, min(4095, key));
    if (key >= B) {
      int pos = atomicAdd(&s_misc[1], 1);
      if (pos < KTOP) {
        u32 gidx = bp[j].y;
        u64 kcomp = ((u64)bits << 32) | (u32)(~gidx);  // score desc, idx asc
        skey[pos] = ~kcomp;                            // inverted -> ascending sort
      }
    }
  }
  __syncthreads();
  const int n = min(s_misc[1], KTOP);
  for (int i = tid; i < KTOP; i += 1024)
    if (i >= n) skey[i] = ~0ull;                        // sentinel sorts last
  __syncthreads();

  // --- 5. bitonic sort ascending on skey (keys only; gidx embedded in low bits)
  for (int kk = 2; kk <= KTOP; kk <<= 1) {
    for (int jj = kk >> 1; jj > 0; jj >>= 1) {
      for (int i = tid; i < KTOP; i += 1024) {
        int ixj = i ^ jj;
        if (ixj > i) {
          u64 a = skey[i], c = skey[ixj];
          bool up = ((i & kk) == 0);
          if ((a > c) == up) { skey[i] = c; skey[ixj] = a; }
        }
      }
      __syncthreads();
    }
  }

  // --- 6. preload first 512 sorted boxes into LDS (recomputed from gidx)
  if (tid < 512 && tid < n) {
    u64 kcomp = ~skey[tid];
    u32 gidx = ~(u32)kcomp;
    pbox[tid] = decode_box_from_gidx(gidx, b, p2, p3, p4, p5);
  }
  __syncthreads();

  // --- 7. sequential NMS on sorted list (wave 0) == greedy argmax NMS
  if (tid < 64) {
    const int lane = tid;
    int sel = 0;
    for (int p = 0; p < KTOP && sel < 100; ++p) {
      u64 ik = skey[p];
      if (ik == ~0ull) break;               // exhausted real candidates
      u64 kcomp = ~ik;
      float sc = __uint_as_float((u32)(kcomp >> 32));
      float4 box = (p < 512) ? pbox[p]
                             : decode_box_from_gidx(~(u32)kcomp, b, p2, p3, p4, p5);
      bool hit = false;
      if (lane < sel) hit = iou_gt(selbox[lane], box);
      if (lane + 64 < sel) hit = hit || iou_gt(selbox[lane + 64], box);
      u64 anyhit = __ballot(hit);
      if (anyhit == 0ull) {
        if (lane == 0) {
          selbox[sel] = box;
          float* orow = out + (size_t)b * 500 + (size_t)sel * 5;
          orow[0] = box.x; orow[1] = box.y; orow[2] = box.z; orow[3] = box.w; orow[4] = sc;
        }
        sel++;
      }
    }
    if (lane == 0) s_misc[2] = sel;
  }
  __syncthreads();

  // --- 8. zero-fill remaining rows
  const int nsel = s_misc[2];
  for (int i = tid; i < (100 - nsel) * 5; i += 1024)
    out[(size_t)b * 500 + (size_t)nsel * 5 + i] = 0.0f;
}

// ---------------------------------------------------------------- launch
extern "C" void kernel_launch(void* const* d_in, const int* in_sizes, int n_in,
                              void* d_out, int out_size, void* d_ws, size_t ws_size,
                              hipStream_t stream) {
  const float* p2 = (const float*)d_in[0];
  const float* p3 = (const float*)d_in[1];
  const float* p4 = (const float*)d_in[2];
  const float* p5 = (const float*)d_in[3];
  float* out = (float*)d_out;

  // ws layout: [counters 256B][pairs uint2 32*C]  (8 B/candidate; full cap = 31.4 MB)
  unsigned char* w = (unsigned char*)d_ws;
  u32* counters = (u32*)w;
  size_t avail = (ws_size > 4096) ? (ws_size - 4096) : 0;
  size_t cap = avail / (32ull * sizeof(uint2));
  int C = (int)((cap < (size_t)NTOT) ? cap : (size_t)NTOT);
  uint2* pairs = (uint2*)(w + 256);

  zero_counters_kernel<<<1, 64, 0, stream>>>(counters);

  decode_kernel<152, 152, 0><<<dim3(361, 32), 256, 0, stream>>>(
      p2, counters, pairs, C, 12.f, 16.f, 19.f, 36.f, 40.f, 28.f, 36.f, 75.f);
  decode_kernel<76, 76, 92416><<<dim3(91, 32), 256, 0, stream>>>(
      p3, counters, pairs, C, 36.f, 75.f, 76.f, 55.f, 72.f, 146.f, 142.f, 110.f);
  decode_kernel<38, 38, 115520><<<dim3(23, 32), 256, 0, stream>>>(
      p4, counters, pairs, C, 72.f, 146.f, 142.f, 110.f, 192.f, 243.f, 459.f, 401.f);
  decode_kernel<19, 19, 121296><<<dim3(6, 32), 256, 0, stream>>>(
      p5, counters, pairs, C, 142.f, 110.f, 192.f, 243.f, 300.f, 300.f, 459.f, 401.f);

  nms_kernel<<<32, 1024, 0, stream>>>(pairs, counters, C, p2, p3, p4, p5, out);
}

// Round 3
// 241.891 us; speedup vs baseline: 3.6765x; 3.6765x over previous
//
#include <hip/hip_runtime.h>
#include <cstdint>
#include <cstddef>

typedef unsigned int u32;
typedef unsigned long long u64;

#define NTOT 122740      // total proposals per batch (4*(152^2+76^2+38^2+19^2))
#define KTOP 2048        // top-K candidates kept per batch for NMS (scan depth ~110-150)
#define SCORE_T 0.25f
#define CSTRIDE 64       // counters padded to 256 B apart (no false sharing)

// level layout: [offset, count) per pyramid level
// L2: [0,      92416)  152x152 stride 4
// L3: [92416,  115520) 76x76   stride 8
// L4: [115520, 121296) 38x38   stride 16
// L5: [121296, 122740) 19x19   stride 32

// ---------------------------------------------------------------- kernel 0
__global__ void zero_counters_kernel(u32* c) {
  int t = blockIdx.x * blockDim.x + threadIdx.x;
  if (t < 32 * CSTRIDE) c[t] = 0u;
}

// ---------------------------------------------------------------- helpers
__device__ __forceinline__ float sigm(float x) { return 1.0f / (1.0f + expf(-x)); }

__device__ float4 decode_box_from_gidx(u32 gidx, int b,
    const float* __restrict__ p2, const float* __restrict__ p3,
    const float* __restrict__ p4, const float* __restrict__ p5)
{
  const float* p; int t, H, W; float stride;
  float aw0, ah0, aw1, ah1, aw2, ah2, aw3, ah3;
  if (gidx < 92416u) {
    p = p2; t = (int)gidx; H = 152; W = 152; stride = 4.0f;
    aw0=12.f; ah0=16.f; aw1=19.f; ah1=36.f; aw2=40.f; ah2=28.f; aw3=36.f; ah3=75.f;
  } else if (gidx < 115520u) {
    p = p3; t = (int)(gidx - 92416u); H = 76; W = 76; stride = 8.0f;
    aw0=36.f; ah0=75.f; aw1=76.f; ah1=55.f; aw2=72.f; ah2=146.f; aw3=142.f; ah3=110.f;
  } else if (gidx < 121296u) {
    p = p4; t = (int)(gidx - 115520u); H = 38; W = 38; stride = 16.0f;
    aw0=72.f; ah0=146.f; aw1=142.f; ah1=110.f; aw2=192.f; ah2=243.f; aw3=459.f; ah3=401.f;
  } else {
    p = p5; t = (int)(gidx - 121296u); H = 19; W = 19; stride = 32.0f;
    aw0=142.f; ah0=110.f; aw1=192.f; ah1=243.f; aw2=300.f; ah2=300.f; aw3=459.f; ah3=401.f;
  }
  int HW = H * W;
  int a = t / HW;
  int r = t - a * HW;
  int y = r / W;
  int x = r - y * W;
  const float* q = p + ((size_t)b * 4 * HW + (size_t)t) * 6;
  float2 t01 = *(const float2*)(q + 0);
  float2 t23 = *(const float2*)(q + 2);
  float cx = (sigm(t01.x) + (float)x) * stride;
  float cy = (sigm(t01.y) + (float)y) * stride;
  float aw = (a == 0) ? aw0 : (a == 1) ? aw1 : (a == 2) ? aw2 : aw3;
  float ah = (a == 0) ? ah0 : (a == 1) ? ah1 : (a == 2) ? ah2 : ah3;
  float bw = expf(t23.x) * aw;
  float bh = expf(t23.y) * ah;
  return make_float4(cx - 0.5f * bw, cy - 0.5f * bh, cx + 0.5f * bw, cy + 0.5f * bh);
}

// ---------------------------------------------------------------- kernel 1
// Block-aggregated compaction: 1 global atomic per block (vs per wave),
// counters padded 256 B apart. Kills the XCD-crossing atomic serialization
// that held R2's decode at 93 GB/s.
template<int H, int W, int OFF>
__global__ void decode_kernel(const float* __restrict__ p, u32* __restrict__ counters,
                              uint2* __restrict__ pairs, int C)
{
  constexpr int HW = H * W;
  constexpr int AHW = 4 * HW;
  const int t = blockIdx.x * blockDim.x + threadIdx.x;
  const int b = blockIdx.y;
  bool inr = (t < AHW);
  float score = -1.0f;
  u32 gidx = 0;
  if (inr) {
    const float* q = p + ((size_t)b * AHW + (size_t)t) * 6;
    float2 t45 = *(const float2*)(q + 4);
    score = sigm(t45.x) * sigm(t45.y);
    gidx = (u32)(OFF + t);
  }
  bool pred = inr && (score >= SCORE_T);
  u64 mask = __ballot(pred);
  const int lane = threadIdx.x & 63;
  const int wid = threadIdx.x >> 6;

  __shared__ u32 s_w[4];
  if (lane == 0) s_w[wid] = (u32)__popcll(mask);
  __syncthreads();
  if (threadIdx.x == 0) {
    u32 c0 = s_w[0], c1 = s_w[1], c2 = s_w[2], c3 = s_w[3];
    u32 tot = c0 + c1 + c2 + c3;
    u32 base = tot ? atomicAdd(&counters[(size_t)b * CSTRIDE], tot) : 0u;
    s_w[0] = base;
    s_w[1] = base + c0;
    s_w[2] = base + c0 + c1;
    s_w[3] = base + c0 + c1 + c2;
  }
  __syncthreads();
  if (pred) {
    u32 pos = s_w[wid] + (u32)__popcll(mask & ((1ull << lane) - 1ull));
    if (pos < (u32)C) {
      pairs[(size_t)b * (size_t)C + pos] = make_uint2(__float_as_uint(score), gidx);
    }
  }
}

// ---------------------------------------------------------------- kernel 2
__device__ __forceinline__ bool iou_gt(float4 A, float4 B) {
  // mirrors reference: inter/(a1+a2-inter+1e-9) > 0.5
  float ltx = fmaxf(A.x, B.x), lty = fmaxf(A.y, B.y);
  float rbx = fminf(A.z, B.z), rby = fminf(A.w, B.w);
  float w = fmaxf(rbx - ltx, 0.0f), h = fmaxf(rby - lty, 0.0f);
  float inter = w * h;
  float a1 = fmaxf(A.z - A.x, 0.0f) * fmaxf(A.w - A.y, 0.0f);
  float a2 = fmaxf(B.z - B.x, 0.0f) * fmaxf(B.w - B.y, 0.0f);
  float iou = inter / (a1 + a2 - inter + 1e-9f);
  return iou > 0.5f;
}

__global__ __launch_bounds__(1024, 1)
void nms_kernel(const uint2* __restrict__ pairs, const u32* __restrict__ counters, int C,
                const float* __restrict__ p2, const float* __restrict__ p3,
                const float* __restrict__ p4, const float* __restrict__ p5,
                float* __restrict__ out)
{
  const int b = blockIdx.x;
  const int tid = threadIdx.x;
  const uint2* bp = pairs + (size_t)b * (size_t)C;

  __shared__ u64 skey[KTOP];        // 16 KB  sort keys (inverted composite, ascending)
  __shared__ u32 hist[4096];        // 16 KB  histogram over score-bit bins
  __shared__ u32 scanbuf[1024];     // 4 KB   group suffix sums
  __shared__ float4 pbox[512];      // 8 KB   preloaded boxes for first 512 sorted
  __shared__ float4 selbox[100];    // 1.6 KB selected boxes
  __shared__ int s_misc[4];         // [0]=cutoff bin B, [1]=lds_n, [2]=n_sel

  int cnt = min((int)counters[(size_t)b * CSTRIDE], C);

  // --- 1. histogram of score bits (scores in [0.25,1) -> bins 0..4095)
  for (int i = tid; i < 4096; i += 1024) hist[i] = 0u;
  if (tid == 0) { s_misc[1] = 0; }
  __syncthreads();
  for (int j = tid; j < cnt; j += 1024) {
    u32 bits = bp[j].x;
    int key = (int)((bits - 0x3E800000u) >> 12);
    key = max(0, min(4095, key));
    atomicAdd(&hist[key], 1u);
  }
  __syncthreads();

  // --- 2. group sums (4 bins/thread) + Hillis-Steele inclusive suffix scan
  u32 g = hist[4 * tid] + hist[4 * tid + 1] + hist[4 * tid + 2] + hist[4 * tid + 3];
  scanbuf[tid] = g;
  __syncthreads();
  for (int off = 1; off < 1024; off <<= 1) {
    u32 v = (tid + off < 1024) ? scanbuf[tid + off] : 0u;
    __syncthreads();
    scanbuf[tid] += v;
    __syncthreads();
  }
  // scanbuf[t] = cnt_ge(4t) = count of keys >= 4t (non-increasing in t)

  // --- 3. cutoff B = min{ b : cnt_ge(b) <= KTOP }  -> keep-set fits, DETERMINISTIC
  if (tid == 0 && scanbuf[0] <= (u32)KTOP) s_misc[0] = 0;   // everything fits: keep all
  {
    u32 nxt = (tid < 1023) ? scanbuf[tid + 1] : 0u;
    if (scanbuf[tid] > (u32)KTOP && nxt <= (u32)KTOP) {     // unique crossing group
      u32 c = nxt;                                          // = cnt_ge(4t+4) <= KTOP
      int B = 4 * tid + 4;
      for (int bin = 4 * tid + 3; bin >= 4 * tid; --bin) {
        c += hist[bin];                                     // = cnt_ge(bin)
        if (c <= (u32)KTOP) B = bin; else break;
      }
      s_misc[0] = B;
    }
  }
  __syncthreads();
  const int B = s_misc[0];

  // --- 4. compact keys >= B into LDS (guaranteed <= KTOP entries, no arbitrary drops)
  for (int j = tid; j < cnt; j += 1024) {
    u32 bits = bp[j].x;
    int key = (int)((bits - 0x3E800000u) >> 12);
    key = max(0, min(4095, key));
    if (key >= B) {
      int pos = atomicAdd(&s_misc[1], 1);
      if (pos < KTOP) {
        u32 gidx = bp[j].y;
        u64 kcomp = ((u64)bits << 32) | (u32)(~gidx);  // score desc, idx asc
        skey[pos] = ~kcomp;                            // inverted -> ascending sort
      }
    }
  }
  __syncthreads();
  const int n = min(s_misc[1], KTOP);
  for (int i = tid; i < KTOP; i += 1024)
    if (i >= n) skey[i] = ~0ull;                        // sentinel sorts last
  __syncthreads();

  // --- 5. bitonic sort ascending on skey (keys only; gidx embedded in low bits)
  for (int kk = 2; kk <= KTOP; kk <<= 1) {
    for (int jj = kk >> 1; jj > 0; jj >>= 1) {
      for (int i = tid; i < KTOP; i += 1024) {
        int ixj = i ^ jj;
        if (ixj > i) {
          u64 a = skey[i], c = skey[ixj];
          bool up = ((i & kk) == 0);
          if ((a > c) == up) { skey[i] = c; skey[ixj] = a; }
        }
      }
      __syncthreads();
    }
  }

  // --- 6. preload first 512 sorted boxes into LDS (recomputed from gidx)
  if (tid < 512 && tid < n) {
    u64 kcomp = ~skey[tid];
    u32 gidx = ~(u32)kcomp;
    pbox[tid] = decode_box_from_gidx(gidx, b, p2, p3, p4, p5);
  }
  __syncthreads();

  // --- 7. sequential NMS on sorted list (wave 0) == greedy argmax NMS
  if (tid < 64) {
    const int lane = tid;
    int sel = 0;
    for (int p = 0; p < KTOP && sel < 100; ++p) {
      u64 ik = skey[p];
      if (ik == ~0ull) break;               // exhausted real candidates
      u64 kcomp = ~ik;
      float sc = __uint_as_float((u32)(kcomp >> 32));
      float4 box = (p < 512) ? pbox[p]
                             : decode_box_from_gidx(~(u32)kcomp, b, p2, p3, p4, p5);
      bool hit = false;
      if (lane < sel) hit = iou_gt(selbox[lane], box);
      if (lane + 64 < sel) hit = hit || iou_gt(selbox[lane + 64], box);
      u64 anyhit = __ballot(hit);
      if (anyhit == 0ull) {
        if (lane == 0) {
          selbox[sel] = box;
          float* orow = out + (size_t)b * 500 + (size_t)sel * 5;
          orow[0] = box.x; orow[1] = box.y; orow[2] = box.z; orow[3] = box.w; orow[4] = sc;
        }
        sel++;
      }
    }
    if (lane == 0) s_misc[2] = sel;
  }
  __syncthreads();

  // --- 8. zero-fill remaining rows
  const int nsel = s_misc[2];
  for (int i = tid; i < (100 - nsel) * 5; i += 1024)
    out[(size_t)b * 500 + (size_t)nsel * 5 + i] = 0.0f;
}

// ---------------------------------------------------------------- launch
extern "C" void kernel_launch(void* const* d_in, const int* in_sizes, int n_in,
                              void* d_out, int out_size, void* d_ws, size_t ws_size,
                              hipStream_t stream) {
  const float* p2 = (const float*)d_in[0];
  const float* p3 = (const float*)d_in[1];
  const float* p4 = (const float*)d_in[2];
  const float* p5 = (const float*)d_in[3];
  float* out = (float*)d_out;

  // ws layout: [counters 32*256B][pairs uint2 32*C]  (8 B/candidate; full cap = 31.4 MB)
  unsigned char* w = (unsigned char*)d_ws;
  u32* counters = (u32*)w;
  const size_t chdr = 32 * CSTRIDE * sizeof(u32);   // 8 KB
  size_t avail = (ws_size > chdr + 4096) ? (ws_size - chdr - 4096) : 0;
  size_t cap = avail / (32ull * sizeof(uint2));
  int C = (int)((cap < (size_t)NTOT) ? cap : (size_t)NTOT);
  uint2* pairs = (uint2*)(w + chdr);

  zero_counters_kernel<<<2, 1024, 0, stream>>>(counters);

  decode_kernel<152, 152, 0><<<dim3(361, 32), 256, 0, stream>>>(p2, counters, pairs, C);
  decode_kernel<76, 76, 92416><<<dim3(91, 32), 256, 0, stream>>>(p3, counters, pairs, C);
  decode_kernel<38, 38, 115520><<<dim3(23, 32), 256, 0, stream>>>(p4, counters, pairs, C);
  decode_kernel<19, 19, 121296><<<dim3(6, 32), 256, 0, stream>>>(p5, counters, pairs, C);

  nms_kernel<<<32, 1024, 0, stream>>>(pairs, counters, C, p2, p3, p4, p5, out);
}

// Round 4
// 192.380 us; speedup vs baseline: 4.6227x; 1.2574x over previous
//
#include <hip/hip_runtime.h>
#include <cstdint>
#include <cstddef>

typedef unsigned int u32;
typedef unsigned long long u64;

#define NTOT 122740      // total proposals per batch (4*(152^2+76^2+38^2+19^2))
#define NQ   (NTOT / 4)  // 30685 uint4 per batch (NTOT % 4 == 0)
#define KTOP 1024        // sorted top-K per batch (expected NMS scan depth ~115)
#define WIN  256         // IoU-matrix window over the sorted list
#define SCORE_T 0.25f
#define TBITS 0x3E800000u   // bit pattern of 0.25f

// level layout: [offset, count) per pyramid level
// L2: [0,      92416)  152x152 stride 4   (4*23104 entries, batch stride 92416*6 floats)
// L3: [92416,  115520) 76x76   stride 8   (4*5776,  batch stride 23104*6)
// L4: [115520, 121296) 38x38   stride 16  (4*1444,  batch stride 5776*6)
// L5: [121296, 122740) 19x19   stride 32  (4*361,   batch stride 1444*6)

// ---------------------------------------------------------------- helpers
__device__ __forceinline__ float sigm(float x) { return 1.0f / (1.0f + expf(-x)); }

__device__ float4 decode_box_from_gidx(u32 gidx, int b,
    const float* __restrict__ p2, const float* __restrict__ p3,
    const float* __restrict__ p4, const float* __restrict__ p5)
{
  const float* p; int t, H, W; float stride;
  float aw0, ah0, aw1, ah1, aw2, ah2, aw3, ah3;
  if (gidx < 92416u) {
    p = p2 + (size_t)b * 92416 * 6; t = (int)gidx; H = 152; W = 152; stride = 4.0f;
    aw0=12.f; ah0=16.f; aw1=19.f; ah1=36.f; aw2=40.f; ah2=28.f; aw3=36.f; ah3=75.f;
  } else if (gidx < 115520u) {
    p = p3 + (size_t)b * 23104 * 6; t = (int)(gidx - 92416u); H = 76; W = 76; stride = 8.0f;
    aw0=36.f; ah0=75.f; aw1=76.f; ah1=55.f; aw2=72.f; ah2=146.f; aw3=142.f; ah3=110.f;
  } else if (gidx < 121296u) {
    p = p4 + (size_t)b * 5776 * 6; t = (int)(gidx - 115520u); H = 38; W = 38; stride = 16.0f;
    aw0=72.f; ah0=146.f; aw1=142.f; ah1=110.f; aw2=192.f; ah2=243.f; aw3=459.f; ah3=401.f;
  } else {
    p = p5 + (size_t)b * 1444 * 6; t = (int)(gidx - 121296u); H = 19; W = 19; stride = 32.0f;
    aw0=142.f; ah0=110.f; aw1=192.f; ah1=243.f; aw2=300.f; ah2=300.f; aw3=459.f; ah3=401.f;
  }
  int HW = H * W;
  int a = t / HW;
  int r = t - a * HW;
  int y = r / W;
  int x = r - y * W;
  const float* q = p + (size_t)t * 6;
  float2 t01 = *(const float2*)(q + 0);
  float2 t23 = *(const float2*)(q + 2);
  float cx = (sigm(t01.x) + (float)x) * stride;
  float cy = (sigm(t01.y) + (float)y) * stride;
  float aw = (a == 0) ? aw0 : (a == 1) ? aw1 : (a == 2) ? aw2 : aw3;
  float ah = (a == 0) ? ah0 : (a == 1) ? ah1 : (a == 2) ? ah2 : ah3;
  float bw = expf(t23.x) * aw;
  float bh = expf(t23.y) * ah;
  return make_float4(cx - 0.5f * bw, cy - 0.5f * bh, cx + 0.5f * bw, cy + 0.5f * bh);
}

__device__ __forceinline__ bool iou_gt(float4 A, float4 B) {
  // mirrors reference: inter/(a1+a2-inter+1e-9) > 0.5
  float ltx = fmaxf(A.x, B.x), lty = fmaxf(A.y, B.y);
  float rbx = fminf(A.z, B.z), rby = fminf(A.w, B.w);
  float w = fmaxf(rbx - ltx, 0.0f), h = fmaxf(rby - lty, 0.0f);
  float inter = w * h;
  float a1 = fmaxf(A.z - A.x, 0.0f) * fmaxf(A.w - A.y, 0.0f);
  float a2 = fmaxf(B.z - B.x, 0.0f) * fmaxf(B.w - B.y, 0.0f);
  float iou = inter / (a1 + a2 - inter + 1e-9f);
  return iou > 0.5f;
}

// bin mapping: valid scores [0.25, 1.0) -> bins 1..4095; invalid stored as 0 bits
__device__ __forceinline__ int score_bin(u32 bits) {
  return min(4095, 1 + (int)((bits - TBITS) >> 12));
}

// ---------------------------------------------------------------- kernel 1
// Pure streaming decode: dense score array, gidx implicit from position.
// Zero atomics, fully coalesced 4B writes. One fused launch for all levels.
__global__ __launch_bounds__(256)
void decode_scores_kernel(const float* __restrict__ p2, const float* __restrict__ p3,
                          const float* __restrict__ p4, const float* __restrict__ p5,
                          u32* __restrict__ scores)
{
  int t = blockIdx.x * 256 + threadIdx.x;
  int b = blockIdx.y;
  if (t >= NTOT) return;
  const float* q;
  if (t < 92416)       q = p2 + ((size_t)b * 92416 + (size_t)t) * 6;
  else if (t < 115520) q = p3 + ((size_t)b * 23104 + (size_t)(t - 92416)) * 6;
  else if (t < 121296) q = p4 + ((size_t)b * 5776  + (size_t)(t - 115520)) * 6;
  else                 q = p5 + ((size_t)b * 1444  + (size_t)(t - 121296)) * 6;
  float2 cc = *(const float2*)(q + 4);              // conf, cls
  float s = sigm(cc.x) * sigm(cc.y);
  scores[(size_t)b * NTOT + t] = (s >= SCORE_T) ? __float_as_uint(s) : 0u;
}

// ---------------------------------------------------------------- kernel 2
__global__ __launch_bounds__(1024, 1)
void topk_nms_kernel(const u32* __restrict__ scores,
                     const float* __restrict__ p2, const float* __restrict__ p3,
                     const float* __restrict__ p4, const float* __restrict__ p5,
                     float* __restrict__ out)
{
  const int b = blockIdx.x;
  const int tid = threadIdx.x;
  const uint4* sp = (const uint4*)(scores + (size_t)b * NTOT);   // 16B-aligned

  __shared__ u64 skey[KTOP];        // 8 KB   sort keys (inverted composite, ascending)
  __shared__ u32 hist[4096];        // 16 KB  histogram over score-bit bins (1..4095)
  __shared__ u32 scanbuf[1024];     // 4 KB   group suffix sums
  __shared__ float4 sbox[WIN];      // 4 KB   boxes for first WIN sorted candidates
  __shared__ u64 smat[WIN * 4];     // 8 KB   IoU>0.5 bitmask matrix, row-major
  __shared__ float4 selbox[100];    // 1.6 KB selected boxes (for slow path)
  __shared__ int s_misc[4];         // [0]=cutoff B, [1]=append cnt, [2]=n_sel, [3]=need slow

  // --- 1. histogram (vectorized uint4 loads, skip invalid -> no bin-0 pileup)
  for (int i = tid; i < 4096; i += 1024) hist[i] = 0u;
  if (tid == 0) { s_misc[1] = 0; s_misc[3] = 0; }
  __syncthreads();
  for (int i = tid; i < NQ; i += 1024) {
    uint4 v = sp[i];
    if (v.x >= TBITS) atomicAdd(&hist[score_bin(v.x)], 1u);
    if (v.y >= TBITS) atomicAdd(&hist[score_bin(v.y)], 1u);
    if (v.z >= TBITS) atomicAdd(&hist[score_bin(v.z)], 1u);
    if (v.w >= TBITS) atomicAdd(&hist[score_bin(v.w)], 1u);
  }
  __syncthreads();

  // --- 2. group sums (4 bins/thread) + Hillis-Steele inclusive suffix scan
  u32 g = hist[4 * tid] + hist[4 * tid + 1] + hist[4 * tid + 2] + hist[4 * tid + 3];
  scanbuf[tid] = g;
  __syncthreads();
  for (int off = 1; off < 1024; off <<= 1) {
    u32 v = (tid + off < 1024) ? scanbuf[tid + off] : 0u;
    __syncthreads();
    scanbuf[tid] += v;
    __syncthreads();
  }
  // scanbuf[t] = cnt_ge(4t), non-increasing in t

  // --- 3. cutoff B = min{ bin : cnt_ge(bin) <= KTOP } (deterministic keep-set)
  if (tid == 0 && scanbuf[0] <= (u32)KTOP) s_misc[0] = 0;
  {
    u32 nxt = (tid < 1023) ? scanbuf[tid + 1] : 0u;
    if (scanbuf[tid] > (u32)KTOP && nxt <= (u32)KTOP) {
      u32 c = nxt;
      int B = 4 * tid + 4;
      for (int bin = 4 * tid + 3; bin >= 4 * tid; --bin) {
        c += hist[bin];
        if (c <= (u32)KTOP) B = bin; else break;
      }
      s_misc[0] = B;
    }
  }
  __syncthreads();
  const int B = max(s_misc[0], 1);   // bin 0 = invalid entries, never kept

  // --- 4. compact keys >= B into LDS (<= KTOP entries, deterministic set)
  for (int i = tid; i < NQ; i += 1024) {
    uint4 v = sp[i];
    u32 c4[4] = { v.x, v.y, v.z, v.w };
    #pragma unroll
    for (int c = 0; c < 4; ++c) {
      u32 bits = c4[c];
      if (bits >= TBITS && score_bin(bits) >= B) {
        int pos = atomicAdd(&s_misc[1], 1);
        if (pos < KTOP) {
          u32 gidx = (u32)(4 * i + c);
          skey[pos] = ~(((u64)bits << 32) | (u32)(~gidx));  // score desc, idx asc
        }
      }
    }
  }
  __syncthreads();
  const int n = min(s_misc[1], KTOP);
  for (int i = tid; i < KTOP; i += 1024)
    if (i >= n) skey[i] = ~0ull;                    // sentinel sorts last
  __syncthreads();

  // --- 5. bitonic sort ascending on skey (1 element per thread, 55 phases)
  for (int kk = 2; kk <= KTOP; kk <<= 1) {
    for (int jj = kk >> 1; jj > 0; jj >>= 1) {
      int i = tid;
      int ixj = i ^ jj;
      if (ixj > i) {
        u64 a = skey[i], c = skey[ixj];
        bool up = ((i & kk) == 0);
        if ((a > c) == up) { skey[i] = c; skey[ixj] = a; }
      }
      __syncthreads();
    }
  }

  const int W = min(n, WIN);

  // --- 6. decode boxes for the top-WIN window
  if (tid < WIN) {
    if (tid < W) {
      u32 gidx = ~(u32)(~skey[tid]);
      sbox[tid] = decode_box_from_gidx(gidx, b, p2, p3, p4, p5);
    } else {
      sbox[tid] = make_float4(0.f, 0.f, 0.f, 0.f);
    }
  }
  __syncthreads();

  // --- 7. IoU bitmask matrix: bit j of row i = iou(box_i, box_j) > 0.5
  {
    int row = tid >> 2, word = tid & 3;
    u64 bits = 0;
    if (row < W) {
      float4 A = sbox[row];
      int j0 = word * 64;
      int jend = min(64, W - j0);
      for (int j = 0; j < jend; ++j)
        if (iou_gt(A, sbox[j0 + j])) bits |= (1ull << j);
    }
    smat[tid] = bits;
  }
  __syncthreads();

  // --- 8. greedy selection = trivial bit-scan (exactly argmax-NMS on sorted order)
  if (tid == 0) {
    u64 s0 = 0, s1 = 0, s2 = 0, s3 = 0;
    int sel = 0;
    for (int p = 0; p < W && sel < 100; ++p) {
      u64 sw = (p < 64) ? s0 : (p < 128) ? s1 : (p < 192) ? s2 : s3;
      if ((sw >> (p & 63)) & 1ull) continue;        // suppressed
      float4 box = sbox[p];
      u64 kcomp = ~skey[p];
      float sc = __uint_as_float((u32)(kcomp >> 32));
      selbox[sel] = box;
      float* orow = out + (size_t)b * 500 + (size_t)sel * 5;
      orow[0] = box.x; orow[1] = box.y; orow[2] = box.z; orow[3] = box.w; orow[4] = sc;
      sel++;
      s0 |= smat[p * 4 + 0]; s1 |= smat[p * 4 + 1];
      s2 |= smat[p * 4 + 2]; s3 |= smat[p * 4 + 3];
    }
    s_misc[2] = sel;
    s_misc[3] = (sel < 100 && n > WIN) ? 1 : 0;
  }
  __syncthreads();

  // --- 9. slow path beyond the window (statistically never taken; exact fallback)
  if (s_misc[3]) {
    if (tid < 64) {
      const int lane = tid;
      int sel = s_misc[2];
      for (int p = WIN; p < n && sel < 100; ++p) {
        u64 kcomp = ~skey[p];
        u32 gidx = ~(u32)kcomp;
        float4 box = decode_box_from_gidx(gidx, b, p2, p3, p4, p5);
        bool hit = false;
        if (lane < sel) hit = iou_gt(selbox[lane], box);
        if (lane + 64 < sel) hit = hit || iou_gt(selbox[lane + 64], box);
        u64 anyhit = __ballot(hit);
        if (anyhit == 0ull) {
          if (lane == 0) {
            selbox[sel] = box;
            float sc = __uint_as_float((u32)(kcomp >> 32));
            float* orow = out + (size_t)b * 500 + (size_t)sel * 5;
            orow[0] = box.x; orow[1] = box.y; orow[2] = box.z; orow[3] = box.w; orow[4] = sc;
          }
          sel++;
        }
      }
      if (lane == 0) s_misc[2] = sel;
    }
  }
  __syncthreads();

  // --- 10. zero-fill remaining rows
  const int nsel = s_misc[2];
  for (int i = tid; i < (100 - nsel) * 5; i += 1024)
    out[(size_t)b * 500 + (size_t)nsel * 5 + i] = 0.0f;
}

// ---------------------------------------------------------------- launch
extern "C" void kernel_launch(void* const* d_in, const int* in_sizes, int n_in,
                              void* d_out, int out_size, void* d_ws, size_t ws_size,
                              hipStream_t stream) {
  const float* p2 = (const float*)d_in[0];
  const float* p3 = (const float*)d_in[1];
  const float* p4 = (const float*)d_in[2];
  const float* p5 = (const float*)d_in[3];
  float* out = (float*)d_out;

  // ws layout: dense score array, 32 * NTOT * 4 B = 15.7 MB
  u32* scores = (u32*)d_ws;

  decode_scores_kernel<<<dim3(480, 32), 256, 0, stream>>>(p2, p3, p4, p5, scores);
  topk_nms_kernel<<<32, 1024, 0, stream>>>(scores, p2, p3, p4, p5, out);
}

// Round 5
// 180.642 us; speedup vs baseline: 4.9231x; 1.0650x over previous
//
#include <hip/hip_runtime.h>
#include <cstdint>
#include <cstddef>

typedef unsigned int u32;
typedef unsigned long long u64;

#define NTOT 122740      // total proposals per batch
#define NQ   30685       // NTOT/4 uint4 per batch
#define NPAIR 61370      // NTOT/2 proposal pairs per batch
#define KTOP 1024        // sorted top-K per batch (expected NMS scan depth ~115)
#define WIN  256         // IoU-matrix window over the sorted list
#define NBIN 4096
#define SCORE_T 0.25f
#define TBITS 0x3E800000u   // bit pattern of 0.25f
#define CSTRIDE 64          // counter padding (u32s) -> 256 B apart

// level layout: [offset, count) per pyramid level (batch strides in floats: N*6)
// L2: [0,      92416)  152x152 s4   N=92416
// L3: [92416,  115520) 76x76   s8   N=23104
// L4: [115520, 121296) 38x38   s16  N=5776
// L5: [121296, 122740) 19x19   s32  N=1444

// ws layout (bytes):
//   hist:     32*4096*4 = 524288   @ 0
//   counters: 32*64*4   = 8192     @ 524288
//   compact:  32*1024*8 = 262144   @ 532480
//   scores:   32*NTOT*4 = 15710720 @ 794624
#define WS_COUNTERS 524288
#define WS_COMPACT  532480
#define WS_SCORES   794624

// ---------------------------------------------------------------- helpers
__device__ __forceinline__ float sigm(float x) { return 1.0f / (1.0f + expf(-x)); }

// valid scores [0.25,1) -> bins 1..4095 (monotone in bits); 0 = invalid
__device__ __forceinline__ int score_bin(u32 bits) {
  return min(4095, 1 + (int)((bits - TBITS) >> 12));
}

__device__ float4 decode_box_from_gidx(u32 gidx, int b,
    const float* __restrict__ p2, const float* __restrict__ p3,
    const float* __restrict__ p4, const float* __restrict__ p5)
{
  const float* p; int t, H, W; float stride;
  float aw0, ah0, aw1, ah1, aw2, ah2, aw3, ah3;
  if (gidx < 92416u) {
    p = p2 + (size_t)b * 92416 * 6; t = (int)gidx; H = 152; W = 152; stride = 4.0f;
    aw0=12.f; ah0=16.f; aw1=19.f; ah1=36.f; aw2=40.f; ah2=28.f; aw3=36.f; ah3=75.f;
  } else if (gidx < 115520u) {
    p = p3 + (size_t)b * 23104 * 6; t = (int)(gidx - 92416u); H = 76; W = 76; stride = 8.0f;
    aw0=36.f; ah0=75.f; aw1=76.f; ah1=55.f; aw2=72.f; ah2=146.f; aw3=142.f; ah3=110.f;
  } else if (gidx < 121296u) {
    p = p4 + (size_t)b * 5776 * 6; t = (int)(gidx - 115520u); H = 38; W = 38; stride = 16.0f;
    aw0=72.f; ah0=146.f; aw1=142.f; ah1=110.f; aw2=192.f; ah2=243.f; aw3=459.f; ah3=401.f;
  } else {
    p = p5 + (size_t)b * 1444 * 6; t = (int)(gidx - 121296u); H = 19; W = 19; stride = 32.0f;
    aw0=142.f; ah0=110.f; aw1=192.f; ah1=243.f; aw2=300.f; ah2=300.f; aw3=459.f; ah3=401.f;
  }
  int HW = H * W;
  int a = t / HW;
  int r = t - a * HW;
  int y = r / W;
  int x = r - y * W;
  const float* q = p + (size_t)t * 6;
  float2 t01 = *(const float2*)(q + 0);
  float2 t23 = *(const float2*)(q + 2);
  float cx = (sigm(t01.x) + (float)x) * stride;
  float cy = (sigm(t01.y) + (float)y) * stride;
  float aw = (a == 0) ? aw0 : (a == 1) ? aw1 : (a == 2) ? aw2 : aw3;
  float ah = (a == 0) ? ah0 : (a == 1) ? ah1 : (a == 2) ? ah2 : ah3;
  float bw = expf(t23.x) * aw;
  float bh = expf(t23.y) * ah;
  return make_float4(cx - 0.5f * bw, cy - 0.5f * bh, cx + 0.5f * bw, cy + 0.5f * bh);
}

__device__ __forceinline__ bool iou_gt(float4 A, float4 B) {
  float ltx = fmaxf(A.x, B.x), lty = fmaxf(A.y, B.y);
  float rbx = fminf(A.z, B.z), rby = fminf(A.w, B.w);
  float w = fmaxf(rbx - ltx, 0.0f), h = fmaxf(rby - lty, 0.0f);
  float inter = w * h;
  float a1 = fmaxf(A.z - A.x, 0.0f) * fmaxf(A.w - A.y, 0.0f);
  float a2 = fmaxf(B.z - B.x, 0.0f) * fmaxf(B.w - B.y, 0.0f);
  float iou = inter / (a1 + a2 - inter + 1e-9f);
  return iou > 0.5f;
}

// ---------------------------------------------------------------- Z: zero hist+counters
__global__ __launch_bounds__(1024)
void zero_kernel(u32* w) {
  int t = blockIdx.x * 1024 + threadIdx.x;   // 130*1024 = 133120 u32 = hist+counters
  if (t < 133120) w[t] = 0u;
}

// ---------------------------------------------------------------- A: decode scores + hist
// Each block: 2048 proposal pairs. Loads ONLY the two float4s per pair containing
// conf/cls (skips box-regression words). Block-local LDS histogram, atomic flush.
__global__ __launch_bounds__(256)
void decode_score_hist(const float* __restrict__ p2, const float* __restrict__ p3,
                       const float* __restrict__ p4, const float* __restrict__ p5,
                       u32* __restrict__ scores, u32* __restrict__ hist)
{
  __shared__ u32 lhist[NBIN];
  const int tid = threadIdx.x;
  const int b = blockIdx.y;
  for (int i = tid; i < NBIN; i += 256) lhist[i] = 0u;
  __syncthreads();

  uint2* srow = (uint2*)(scores + (size_t)b * NTOT);
  const int pbase = blockIdx.x * 2048;
  #pragma unroll 2
  for (int k = 0; k < 8; ++k) {
    int P = pbase + k * 256 + tid;
    if (P < NPAIR) {
      int t0 = 2 * P;
      const float* p; int l0, LN;
      if (t0 < 92416)       { p = p2; l0 = t0;          LN = 92416; }
      else if (t0 < 115520) { p = p3; l0 = t0 - 92416;  LN = 23104; }
      else if (t0 < 121296) { p = p4; l0 = t0 - 115520; LN = 5776;  }
      else                  { p = p5; l0 = t0 - 121296; LN = 1444;  }
      // l0 even & LN even -> both float4 loads 16B-aligned
      const float* q = p + ((size_t)b * LN + (size_t)l0) * 6 + 4;
      float4 v1 = *(const float4*)(q);      // conf0, cls0, t0_1, t1_1
      float4 v2 = *(const float4*)(q + 4);  // t2_1, t3_1, conf1, cls1
      float s0 = sigm(v1.x) * sigm(v1.y);
      float s1 = sigm(v2.z) * sigm(v2.w);
      u32 b0 = (s0 >= SCORE_T) ? __float_as_uint(s0) : 0u;
      u32 b1 = (s1 >= SCORE_T) ? __float_as_uint(s1) : 0u;
      srow[P] = make_uint2(b0, b1);
      if (b0) atomicAdd(&lhist[score_bin(b0)], 1u);
      if (b1) atomicAdd(&lhist[score_bin(b1)], 1u);
    }
  }
  __syncthreads();
  u32* gh = hist + (size_t)b * NBIN;
  for (int i = tid; i < NBIN; i += 256) {
    u32 v = lhist[i];
    if (v) atomicAdd(&gh[i], v);
  }
}

// ---------------------------------------------------------------- B1: cutoff + filter
// 15 blocks/batch; each recomputes cutoff B from global hist (cheap), scans its
// 8192-proposal slice, appends survivors (deterministic set, <=KTOP/batch) via
// LDS staging + ONE global atomic per block.
__global__ __launch_bounds__(256)
void filter_kernel(const u32* __restrict__ scores, const u32* __restrict__ hist,
                   u32* __restrict__ counters, uint2* __restrict__ compact)
{
  __shared__ u32 shist[NBIN];
  __shared__ u32 scan[256];
  __shared__ uint2 cand[KTOP];
  __shared__ u32 s_cnt, s_base;
  __shared__ int s_B;
  const int tid = threadIdx.x;
  const int b = blockIdx.y;

  const u32* gh = hist + (size_t)b * NBIN;
  for (int i = tid; i < NBIN; i += 256) shist[i] = gh[i];
  if (tid == 0) s_cnt = 0u;
  __syncthreads();

  // suffix counts: scan[t] = cnt_ge(16t)
  u32 g = 0;
  const int base = tid * 16;
  #pragma unroll
  for (int k = 0; k < 16; ++k) g += shist[base + k];
  scan[tid] = g;
  __syncthreads();
  for (int off = 1; off < 256; off <<= 1) {
    u32 v = (tid + off < 256) ? scan[tid + off] : 0u;
    __syncthreads();
    scan[tid] += v;
    __syncthreads();
  }
  // cutoff B = min{ bin : cnt_ge(bin) <= KTOP }  (deterministic keep-set)
  if (tid == 0 && scan[0] <= (u32)KTOP) s_B = 1;
  {
    u32 nxt = (tid < 255) ? scan[tid + 1] : 0u;
    if (scan[tid] > (u32)KTOP && nxt <= (u32)KTOP) {
      u32 c = nxt;
      int Bv = base + 16;
      for (int bin = base + 15; bin >= base; --bin) {
        c += shist[bin];
        if (c <= (u32)KTOP) Bv = bin; else break;
      }
      s_B = Bv;
    }
  }
  __syncthreads();
  const int B = max(s_B, 1);

  // scan slice (coalesced uint4), stage survivors in LDS
  const uint4* sp = (const uint4*)(scores + (size_t)b * NTOT);
  const int i0 = blockIdx.x * 2048;
  const int i1 = min(i0 + 2048, NQ);
  for (int i = i0 + tid; i < i1; i += 256) {
    uint4 v = sp[i];
    u32 c4[4] = { v.x, v.y, v.z, v.w };
    #pragma unroll
    for (int c = 0; c < 4; ++c) {
      u32 bits = c4[c];
      if (bits && score_bin(bits) >= B) {
        u32 pos = atomicAdd(&s_cnt, 1u);
        if (pos < (u32)KTOP) cand[pos] = make_uint2(bits, (u32)(4 * i + c));
      }
    }
  }
  __syncthreads();
  const u32 m = min(s_cnt, (u32)KTOP);
  if (tid == 0) s_base = m ? atomicAdd(&counters[(size_t)b * CSTRIDE], m) : 0u;
  __syncthreads();
  const u32 gbase = s_base;
  uint2* crow = compact + (size_t)b * KTOP;
  for (u32 i = tid; i < m; i += 256) {
    u32 dst = gbase + i;
    if (dst < (u32)KTOP) crow[dst] = cand[i];
  }
}

// ---------------------------------------------------------------- B2: sort + NMS
__global__ __launch_bounds__(1024, 1)
void sort_nms_kernel(const uint2* __restrict__ compact, const u32* __restrict__ counters,
                     const float* __restrict__ p2, const float* __restrict__ p3,
                     const float* __restrict__ p4, const float* __restrict__ p5,
                     float* __restrict__ out)
{
  const int b = blockIdx.x;
  const int tid = threadIdx.x;

  __shared__ u64 skey[KTOP];        // 8 KB
  __shared__ float4 sbox[WIN];      // 4 KB
  __shared__ u64 smat[WIN * 4];     // 8 KB IoU>0.5 bitmask matrix
  __shared__ float4 selbox[100];    // 1.6 KB
  __shared__ int s_misc[4];         // [2]=n_sel, [3]=need slow

  const int n = min((int)counters[(size_t)b * CSTRIDE], KTOP);
  const uint2* crow = compact + (size_t)b * KTOP;
  if (tid < n) {
    uint2 pr = crow[tid];
    skey[tid] = ~(((u64)pr.x << 32) | (u32)(~pr.y));   // score desc, idx asc
  } else {
    skey[tid] = ~0ull;                                 // sentinel sorts last
  }
  __syncthreads();

  // bitonic sort ascending, 1 elem/thread, 55 phases
  for (int kk = 2; kk <= KTOP; kk <<= 1) {
    for (int jj = kk >> 1; jj > 0; jj >>= 1) {
      int i = tid, ixj = i ^ jj;
      if (ixj > i) {
        u64 a = skey[i], c = skey[ixj];
        bool up = ((i & kk) == 0);
        if ((a > c) == up) { skey[i] = c; skey[ixj] = a; }
      }
      __syncthreads();
    }
  }

  const int Wn = min(n, WIN);

  // decode boxes for the window
  if (tid < WIN) {
    sbox[tid] = (tid < Wn) ? decode_box_from_gidx(~(u32)(~skey[tid]), b, p2, p3, p4, p5)
                           : make_float4(0.f, 0.f, 0.f, 0.f);
  }
  __syncthreads();

  // IoU bitmask matrix: bit j of row i = iou(box_i, box_j) > 0.5
  {
    int row = tid >> 2, word = tid & 3;
    u64 bits = 0;
    if (row < Wn) {
      float4 A = sbox[row];
      int j0 = word * 64;
      int je = min(64, Wn - j0);
      for (int j = 0; j < je; ++j)
        if (iou_gt(A, sbox[j0 + j])) bits |= (1ull << j);
    }
    smat[tid] = bits;
  }
  __syncthreads();

  // greedy selection = bit-scan over sorted order (== argmax-NMS)
  if (tid == 0) {
    u64 s0 = 0, s1 = 0, s2 = 0, s3 = 0;
    int sel = 0;
    for (int p = 0; p < Wn && sel < 100; ++p) {
      u64 sw = (p < 64) ? s0 : (p < 128) ? s1 : (p < 192) ? s2 : s3;
      if ((sw >> (p & 63)) & 1ull) continue;
      float4 box = sbox[p];
      u64 kcomp = ~skey[p];
      float sc = __uint_as_float((u32)(kcomp >> 32));
      selbox[sel] = box;
      float* orow = out + (size_t)b * 500 + (size_t)sel * 5;
      orow[0] = box.x; orow[1] = box.y; orow[2] = box.z; orow[3] = box.w; orow[4] = sc;
      sel++;
      s0 |= smat[p * 4 + 0]; s1 |= smat[p * 4 + 1];
      s2 |= smat[p * 4 + 2]; s3 |= smat[p * 4 + 3];
    }
    s_misc[2] = sel;
    s_misc[3] = (sel < 100 && n > WIN) ? 1 : 0;
  }
  __syncthreads();

  // exact slow path beyond the window (statistically never taken)
  if (s_misc[3]) {
    if (tid < 64) {
      const int lane = tid;
      int sel = s_misc[2];
      for (int p = WIN; p < n && sel < 100; ++p) {
        u64 kcomp = ~skey[p];
        float4 box = decode_box_from_gidx(~(u32)kcomp, b, p2, p3, p4, p5);
        bool hit = false;
        if (lane < sel) hit = iou_gt(selbox[lane], box);
        if (lane + 64 < sel) hit = hit || iou_gt(selbox[lane + 64], box);
        u64 anyhit = __ballot(hit);
        if (anyhit == 0ull) {
          if (lane == 0) {
            selbox[sel] = box;
            float sc = __uint_as_float((u32)(kcomp >> 32));
            float* orow = out + (size_t)b * 500 + (size_t)sel * 5;
            orow[0] = box.x; orow[1] = box.y; orow[2] = box.z; orow[3] = box.w; orow[4] = sc;
          }
          sel++;
        }
      }
      if (lane == 0) s_misc[2] = sel;
    }
  }
  __syncthreads();

  // zero-fill remaining rows
  const int nsel = s_misc[2];
  for (int i = tid; i < (100 - nsel) * 5; i += 1024)
    out[(size_t)b * 500 + (size_t)nsel * 5 + i] = 0.0f;
}

// ---------------------------------------------------------------- launch
extern "C" void kernel_launch(void* const* d_in, const int* in_sizes, int n_in,
                              void* d_out, int out_size, void* d_ws, size_t ws_size,
                              hipStream_t stream) {
  const float* p2 = (const float*)d_in[0];
  const float* p3 = (const float*)d_in[1];
  const float* p4 = (const float*)d_in[2];
  const float* p5 = (const float*)d_in[3];
  float* out = (float*)d_out;

  unsigned char* w = (unsigned char*)d_ws;
  u32*   hist     = (u32*)w;
  u32*   counters = (u32*)(w + WS_COUNTERS);
  uint2* compact  = (uint2*)(w + WS_COMPACT);
  u32*   scores   = (u32*)(w + WS_SCORES);

  zero_kernel<<<130, 1024, 0, stream>>>(hist);
  decode_score_hist<<<dim3(30, 32), 256, 0, stream>>>(p2, p3, p4, p5, scores, hist);
  filter_kernel<<<dim3(15, 32), 256, 0, stream>>>(scores, hist, counters, compact);
  sort_nms_kernel<<<32, 1024, 0, stream>>>(compact, counters, p2, p3, p4, p5, out);
}